// Round 4
// baseline (1239.509 us; speedup 1.0000x reference)
//
#include <hip/hip_runtime.h>
#include <stdint.h>

#define NN 4096
#define DF 128
#define NBINS (1 << 20)
#define CHUNK 4096
#define NCHUNKS (NBINS / CHUNK)   // 256
#define BORUVKA_ROUNDS 12
#define NXCD 8

typedef __attribute__((ext_vector_type(8))) short short8;
typedef __attribute__((ext_vector_type(4))) float floatx4;

// ---------- helpers ----------
__device__ __forceinline__ unsigned bin_of(float v, float scale) {
  if (v < 0.f) v = 0.f;
  unsigned b = (unsigned)(v * scale);
  return b >= (unsigned)NBINS ? (unsigned)(NBINS - 1) : b;
}

// physical XCD id (0..7) [measured: learn_hip m09 — HW_REG_XCC_ID=20, bits 3:0]
__device__ __forceinline__ int xcc_id() {
  return (int)(__builtin_amdgcn_s_getreg((3u << 11) | (0u << 6) | 20u)) & (NXCD - 1);
}

// ---------- row squared norms for both graphs (fp32, matches reference) ----------
__global__ void k_rownorm(const float* __restrict__ x1, const float* __restrict__ x2,
                          float* __restrict__ sq) {
  int i = blockIdx.x * blockDim.x + threadIdx.x;
  if (i >= 2 * NN) return;
  const float* x = (i < NN) ? x1 : x2;
  int r = i & (NN - 1);
  const float* row = x + (size_t)r * DF;
  float s = 0.f;
  for (int k = 0; k < DF; ++k) s += row[k] * row[k];
  sq[i] = s;
}

// ---------- split fp32 -> (hi, lo) bf16 for error-compensated MFMA ----------
__global__ void k_split(const float* __restrict__ x1, const float* __restrict__ x2,
                        unsigned short* __restrict__ xh, unsigned short* __restrict__ xl) {
  int i = blockIdx.x * blockDim.x + threadIdx.x;
  if (i >= 2 * NN * DF) return;
  const float* x = (i < NN * DF) ? x1 : x2;
  float v = x[i & (NN * DF - 1)];
  unsigned u = __float_as_uint(v);
  unsigned hu = u & 0xffff0000u;
  float hf = __uint_as_float(hu);
  float lf = v - hf;
  unsigned lu = __float_as_uint(lf) & 0xffff0000u;
  xh[i] = (unsigned short)(hu >> 16);
  xl[i] = (unsigned short)(lu >> 16);
}

// ---------- distance matrix via split-bf16 MFMA Gram ----------
__global__ __launch_bounds__(256) void k_dist(const unsigned short* __restrict__ Xhi,
                                              const unsigned short* __restrict__ Xlo,
                                              const float* __restrict__ sq,
                                              float* __restrict__ Dbase,
                                              unsigned* __restrict__ caps) {
  int g = blockIdx.z;
  const unsigned short* xh = Xhi + (size_t)g * NN * DF;
  const unsigned short* xl = Xlo + (size_t)g * NN * DF;
  const float* sqg = sq + g * NN;
  float* D = Dbase + (size_t)g * NN * NN;
  __shared__ __align__(16) unsigned short Ah[64 * 32];
  __shared__ __align__(16) unsigned short Al[64 * 32];
  __shared__ __align__(16) unsigned short Bh[64 * 32];
  __shared__ __align__(16) unsigned short Bl[64 * 32];
  int i0 = blockIdx.y * 64, j0 = blockIdx.x * 64;
  int t = threadIdx.x;
  int w = t >> 6, lane = t & 63;
  int m = lane & 15, quad = lane >> 4;
  floatx4 acc[4];
  for (int s = 0; s < 4; ++s) acc[s] = (floatx4){0.f, 0.f, 0.f, 0.f};
  int srow = t >> 2, skp = (t & 3) * 8;
  for (int kc = 0; kc < DF; kc += 32) {
    if (kc) __syncthreads();
    *(short8*)&Ah[srow * 32 + skp] = *(const short8*)&xh[(size_t)(i0 + srow) * DF + kc + skp];
    *(short8*)&Al[srow * 32 + skp] = *(const short8*)&xl[(size_t)(i0 + srow) * DF + kc + skp];
    *(short8*)&Bh[srow * 32 + skp] = *(const short8*)&xh[(size_t)(j0 + srow) * DF + kc + skp];
    *(short8*)&Bl[srow * 32 + skp] = *(const short8*)&xl[(size_t)(j0 + srow) * DF + kc + skp];
    __syncthreads();
    short8 ah = *(const short8*)&Ah[(w * 16 + m) * 32 + quad * 8];
    short8 al = *(const short8*)&Al[(w * 16 + m) * 32 + quad * 8];
    for (int s = 0; s < 4; ++s) {
      short8 bh = *(const short8*)&Bh[(s * 16 + m) * 32 + quad * 8];
      short8 bl = *(const short8*)&Bl[(s * 16 + m) * 32 + quad * 8];
      acc[s] = __builtin_amdgcn_mfma_f32_16x16x32_bf16(ah, bh, acc[s], 0, 0, 0);
      acc[s] = __builtin_amdgcn_mfma_f32_16x16x32_bf16(ah, bl, acc[s], 0, 0, 0);
      acc[s] = __builtin_amdgcn_mfma_f32_16x16x32_bf16(al, bh, acc[s], 0, 0, 0);
    }
  }
  float mx = 0.f;
  int ib = i0 + w * 16 + quad * 4;
  for (int s = 0; s < 4; ++s) {
    int j = j0 + s * 16 + m;
    float sqj = sqg[j];
    for (int r = 0; r < 4; ++r) {
      int i = ib + r;
      float d2 = sqg[i] + sqj - 2.f * acc[s][r];
      d2 = fmaxf(d2, 0.f);
      float d = (d2 > 1e-12f) ? sqrtf(d2) : 0.f;
      mx = fmaxf(mx, d);
      D[(size_t)i * NN + j] = d;
    }
  }
  for (int off = 32; off > 0; off >>= 1) mx = fmaxf(mx, __shfl_down(mx, off, 64));
  __shared__ float wmax[4];
  if (lane == 0) wmax[w] = mx;
  __syncthreads();
  if (t == 0) {
    float mm = fmaxf(fmaxf(wmax[0], wmax[1]), fmaxf(wmax[2], wmax[3]));
    atomicMax(&caps[g], __float_as_uint(mm));
  }
}

// ---------- Boruvka init ----------
__global__ void k_binit(int* __restrict__ comp, unsigned long long* __restrict__ compbest,
                        int* __restrict__ mstcnt, int* __restrict__ ncomp) {
  int i = blockIdx.x * blockDim.x + threadIdx.x;
  if (i >= 2 * NN) return;
  comp[i] = i & (NN - 1);
  compbest[i] = ~0ull;
  if ((i & (NN - 1)) == 0) {
    mstcnt[i >> 12] = 0;
    ncomp[i >> 12] = NN;
  }
}

// ---------- Boruvka step 1: per-row min edge leaving own component ----------
__global__ __launch_bounds__(256) void k_minedge(const float* __restrict__ Dbase,
                                                 const int* __restrict__ comp_base,
                                                 unsigned long long* __restrict__ compbest_base,
                                                 const int* __restrict__ ncomp) {
  int g = blockIdx.y;
  if (ncomp[g] == 1) return;
  int v = blockIdx.x;
  const float* row = Dbase + ((size_t)g * NN + (size_t)v) * NN;
  const int* comp = comp_base + g * NN;
  unsigned long long* cbest = compbest_base + (size_t)g * NN;
  int cv = comp[v];
  int t = threadIdx.x;
  unsigned long long best = ~0ull;
  for (int j = t; j < NN; j += 256) {
    if (comp[j] != cv) {
      unsigned long long key = ((unsigned long long)__float_as_uint(row[j]) << 24) |
                               ((unsigned)v << 12) | (unsigned)j;
      if (key < best) best = key;
    }
  }
  for (int off = 32; off > 0; off >>= 1) {
    unsigned long long o = __shfl_down(best, off, 64);
    if (o < best) best = o;
  }
  __shared__ unsigned long long wmin[4];
  if ((t & 63) == 0) wmin[t >> 6] = best;
  __syncthreads();
  if (t == 0) {
    unsigned long long bb = wmin[0];
    for (int w = 1; w < 4; ++w)
      if (wmin[w] < bb) bb = wmin[w];
    if (bb != ~0ull) atomicMin(&cbest[cv], bb);
  }
}

// ---------- Boruvka step 2: hook/contract ----------
__global__ __launch_bounds__(1024) void k_hook(unsigned long long* __restrict__ compbest_base,
                                               int* __restrict__ comp_base,
                                               float* __restrict__ mstw_base,
                                               int* __restrict__ mstcnt,
                                               int* __restrict__ ncomp) {
  int g = blockIdx.x;
  if (ncomp[g] == 1) return;
  unsigned long long* cb = compbest_base + (size_t)g * NN;
  int* comp = comp_base + g * NN;
  float* mstw = mstw_base + g * (NN - 1);
  __shared__ int par[NN];
  __shared__ unsigned char live[NN];
  __shared__ int newcnt;
  int t = threadIdx.x;
  if (t == 0) newcnt = 0;
  for (int c = t; c < NN; c += 1024) {
    unsigned long long key = cb[c];
    bool a = (key != ~0ull);
    live[c] = a ? 1 : 0;
    int p = c;
    if (a) {
      int j = (int)(key & 0xfffull);
      p = comp[j];
    }
    par[c] = p;
  }
  __syncthreads();
  for (int c = t; c < NN; c += 1024) {
    int p = par[c];
    if (p != c && par[p] == c && c < p) par[c] = c;
  }
  __syncthreads();
  for (int c = t; c < NN; c += 1024) {
    if (live[c] && par[c] != c) {
      unsigned long long key = cb[c];
      float w = __uint_as_float((unsigned)(key >> 24));
      int slot = atomicAdd(&mstcnt[g], 1);
      mstw[slot] = w;
    }
  }
  __syncthreads();
  for (int it = 0; it < 12; ++it) {
    int np[NN / 1024];
    for (int c = t, k = 0; c < NN; c += 1024, ++k) np[k] = par[par[c]];
    __syncthreads();
    for (int c = t, k = 0; c < NN; c += 1024, ++k) par[c] = np[k];
    __syncthreads();
  }
  int cnt = 0;
  for (int c = t; c < NN; c += 1024)
    if (live[c] && par[c] == c) cnt++;
  for (int off = 32; off > 0; off >>= 1) cnt += __shfl_down(cnt, off, 64);
  if ((t & 63) == 0 && cnt) atomicAdd(&newcnt, cnt);
  for (int v = t; v < NN; v += 1024) comp[v] = par[comp[v]];
  for (int c = t; c < NN; c += 1024) cb[c] = ~0ull;
  __syncthreads();
  if (t == 0) ncomp[g] = newcnt;
}

// ---------- histogram: upper triangle, per-XCD private copies,
//            workgroup-scope atomics (stay in local XCD L2) ----------
// H layout: [xcd][g][NBINS]; all updaters of copy x run on XCD x => one L2.
__global__ __launch_bounds__(256) void k_hist(const float* __restrict__ Dbase,
                                              const unsigned* __restrict__ caps,
                                              unsigned* __restrict__ H) {
  int g = blockIdx.y;
  const float* D = Dbase + (size_t)g * NN * NN;
  unsigned* hist = H + ((size_t)(xcc_id() * 2 + g)) * NBINS;
  float cap = __uint_as_float(caps[g]);
  float capmax = fmaxf(__uint_as_float(caps[0]), __uint_as_float(caps[1]));
  float scale = (float)NBINS / capmax;
  int x = blockIdx.x;
  int r1 = x, r2 = NN - 1 - x;
  const float* row1 = D + (size_t)r1 * NN;
  const float* row2 = D + (size_t)r2 * NN;
  for (int j = r1 + 1 + threadIdx.x; j < NN; j += 256)
    __hip_atomic_fetch_add(&hist[bin_of(cap - row1[j], scale)], 1u,
                           __ATOMIC_RELAXED, __HIP_MEMORY_SCOPE_WORKGROUP);
  for (int j = r2 + 1 + threadIdx.x; j < NN; j += 256)
    __hip_atomic_fetch_add(&hist[bin_of(cap - row2[j], scale)], 1u,
                           __ATOMIC_RELAXED, __HIP_MEMORY_SCOPE_WORKGROUP);
}

// ---------- move tree edges to persistence 0 (device-scope; wrap-safe) ----------
__global__ void k_treefix(const float* __restrict__ twbase, const unsigned* __restrict__ caps,
                          unsigned* __restrict__ H) {
  int g = blockIdx.y;
  unsigned* hist = H + (size_t)g * NBINS;  // copy 0 of this graph
  float cap = __uint_as_float(caps[g]);
  float capmax = fmaxf(__uint_as_float(caps[0]), __uint_as_float(caps[1]));
  float scale = (float)NBINS / capmax;
  int idx = blockIdx.x * blockDim.x + threadIdx.x;
  if (idx < NN - 1) {
    float w = twbase[g * (NN - 1) + idx];
    atomicSub(&hist[bin_of(cap - w, scale)], 1u);  // may wrap; sum mod 2^32 is exact
    atomicAdd(&hist[0], 1u);
  }
}

// ---------- scan phase A: per-chunk sums of (H1 - H2), merging 8 copies ----------
__global__ __launch_bounds__(256) void k_blocksum(const unsigned* __restrict__ H,
                                                  long long* __restrict__ csum) {
  int b = blockIdx.x, t = threadIdx.x;
  int base = b * CHUNK;
  long long s = 0;
  for (int i = t; i < CHUNK; i += 256) {
    unsigned s1 = 0, s2 = 0;
    for (int x = 0; x < NXCD; ++x) {
      s1 += H[((size_t)(2 * x)) * NBINS + base + i];
      s2 += H[((size_t)(2 * x + 1)) * NBINS + base + i];
    }
    s += (long long)(int)(s1 - s2);
  }
  for (int off = 32; off > 0; off >>= 1) s += __shfl_down(s, off, 64);
  __shared__ long long wsum[4];
  if ((t & 63) == 0) wsum[t >> 6] = s;
  __syncthreads();
  if (t == 0) csum[b] = wsum[0] + wsum[1] + wsum[2] + wsum[3];
}

// ---------- scan phase B: exclusive scan of chunk sums ----------
__global__ __launch_bounds__(NCHUNKS) void k_scanoff(const long long* __restrict__ csum,
                                                     long long* __restrict__ coffs) {
  __shared__ long long sh[NCHUNKS];
  int t = threadIdx.x;
  sh[t] = csum[t];
  __syncthreads();
  for (int off = 1; off < NCHUNKS; off <<= 1) {
    long long v = (t >= off) ? sh[t - off] : 0;
    __syncthreads();
    sh[t] += v;
    __syncthreads();
  }
  coffs[t] = sh[t] - csum[t];
}

// ---------- scan phase C: sum |running prefix| exactly ----------
__global__ __launch_bounds__(256) void k_final(const unsigned* __restrict__ H,
                                               const long long* __restrict__ coffs,
                                               unsigned long long* __restrict__ acc) {
  int b = blockIdx.x, t = threadIdx.x;
  int base = b * CHUNK + t * 16;
  long long v[16];
  long long tsum = 0;
  for (int r = 0; r < 16; ++r) {
    unsigned s1 = 0, s2 = 0;
    for (int x = 0; x < NXCD; ++x) {
      s1 += H[((size_t)(2 * x)) * NBINS + base + r];
      s2 += H[((size_t)(2 * x + 1)) * NBINS + base + r];
    }
    v[r] = (long long)(int)(s1 - s2);
    tsum += v[r];
  }
  int lane = t & 63, wid = t >> 6;
  long long incl = tsum;
  for (int off = 1; off < 64; off <<= 1) {
    long long o = __shfl_up(incl, off, 64);
    if (lane >= off) incl += o;
  }
  __shared__ long long wtot[4];
  if (lane == 63) wtot[wid] = incl;
  __syncthreads();
  long long woff = 0;
  for (int w = 0; w < wid; ++w) woff += wtot[w];
  long long run = coffs[b] + woff + (incl - tsum);
  unsigned long long local = 0;
  for (int r = 0; r < 16; ++r) {
    run += v[r];
    local += (unsigned long long)(run < 0 ? -run : run);
  }
  for (int off = 32; off > 0; off >>= 1) local += __shfl_down(local, off, 64);
  __shared__ unsigned long long wl[4];
  if (lane == 0) wl[wid] = local;
  __syncthreads();
  if (t == 0) atomicAdd(acc, wl[0] + wl[1] + wl[2] + wl[3]);
}

// ---------- output ----------
__global__ void k_out(const unsigned long long* __restrict__ acc,
                      const unsigned* __restrict__ caps, float* __restrict__ out) {
  float capmax = fmaxf(__uint_as_float(caps[0]), __uint_as_float(caps[1]));
  double dt = (double)capmax / (double)NBINS;
  out[0] = (float)((double)(*acc) * dt);
}

__global__ void k_fail(float* out) { out[0] = -1234567.0f; }

extern "C" void kernel_launch(void* const* d_in, const int* in_sizes, int n_in,
                              void* d_out, int out_size, void* d_ws, size_t ws_size,
                              hipStream_t stream) {
  const float* x1 = (const float*)d_in[0];
  const float* x2 = (const float*)d_in[2];
  float* out = (float*)d_out;
  char* ws = (char*)d_ws;

  const size_t offD = 0;                                          // 128 MiB D matrices
  const size_t offH = 2ull * NN * NN * 4ull;                      // 16 copies x 4 MiB = 64 MiB
  const size_t offHdr = offH + 16ull * (size_t)NBINS * 4ull;      // caps(8)+acc(8)+pad
  const size_t offSq = offHdr + 64;
  const size_t offTw = offSq + 2ull * NN * 4ull;
  const size_t offCs = (offTw + 2ull * (NN - 1) * 4ull + 7ull) & ~7ull;
  const size_t offCo = offCs + (size_t)NCHUNKS * 8ull;
  const size_t offCb = offCo + (size_t)NCHUNKS * 8ull;
  const size_t offCp = offCb + 2ull * NN * 8ull;
  const size_t offMeta = offCp + 2ull * NN * 4ull;
  const size_t needed = offMeta + 64;
  if (ws_size < needed) {
    hipLaunchKernelGGL(k_fail, dim3(1), dim3(1), 0, stream, out);
    return;
  }

  float* Dbase = (float*)(ws + offD);
  unsigned* H = (unsigned*)(ws + offH);
  // Xhi/Xlo (2 MiB each) transiently occupy copy-0/g0's 4 MiB; re-zeroed after k_dist.
  unsigned short* Xhi = (unsigned short*)(ws + offH);
  unsigned short* Xlo = (unsigned short*)(ws + offH + 2ull * NN * DF * 2ull);
  unsigned* caps = (unsigned*)(ws + offHdr);
  unsigned long long* acc = (unsigned long long*)(ws + offHdr + 8);
  float* sq = (float*)(ws + offSq);
  float* tw = (float*)(ws + offTw);
  long long* csum = (long long*)(ws + offCs);
  long long* coffs = (long long*)(ws + offCo);
  unsigned long long* compbest = (unsigned long long*)(ws + offCb);
  int* comp = (int*)(ws + offCp);
  int* mstcnt = (int*)(ws + offMeta);
  int* ncomp = (int*)(ws + offMeta + 8);

  // zero all 16 histogram copies + caps + acc
  hipMemsetAsync(ws + offH, 0, 16ull * (size_t)NBINS * 4ull + 64, stream);

  hipLaunchKernelGGL(k_rownorm, dim3((2 * NN + 255) / 256), dim3(256), 0, stream, x1, x2, sq);
  hipLaunchKernelGGL(k_split, dim3((2 * NN * DF + 255) / 256), dim3(256), 0, stream,
                     x1, x2, Xhi, Xlo);
  hipLaunchKernelGGL(k_dist, dim3(64, 64, 2), dim3(256), 0, stream, Xhi, Xlo, sq, Dbase, caps);
  // re-zero the copy-0 region that held Xhi/Xlo
  hipMemsetAsync(ws + offH, 0, 4ull * NN * DF * 2ull, stream);
  hipLaunchKernelGGL(k_binit, dim3((2 * NN + 255) / 256), dim3(256), 0, stream,
                     comp, compbest, mstcnt, ncomp);
  for (int r = 0; r < BORUVKA_ROUNDS; ++r) {
    hipLaunchKernelGGL(k_minedge, dim3(NN, 2), dim3(256), 0, stream,
                       Dbase, comp, compbest, ncomp);
    hipLaunchKernelGGL(k_hook, dim3(2), dim3(1024), 0, stream,
                       compbest, comp, tw, mstcnt, ncomp);
  }
  hipLaunchKernelGGL(k_hist, dim3(NN / 2, 2), dim3(256), 0, stream, Dbase, caps, H);
  hipLaunchKernelGGL(k_treefix, dim3(16, 2), dim3(256), 0, stream, tw, caps, H);
  hipLaunchKernelGGL(k_blocksum, dim3(NCHUNKS), dim3(256), 0, stream, H, csum);
  hipLaunchKernelGGL(k_scanoff, dim3(1), dim3(NCHUNKS), 0, stream, csum, coffs);
  hipLaunchKernelGGL(k_final, dim3(NCHUNKS), dim3(256), 0, stream, H, coffs, acc);
  hipLaunchKernelGGL(k_out, dim3(1), dim3(1), 0, stream, acc, caps, out);
}

// Round 5
// 568.043 us; speedup vs baseline: 2.1821x; 2.1821x over previous
//
#include <hip/hip_runtime.h>
#include <stdint.h>

#define NN 4096
#define DF 128
#define NBINS 16384          // fine bins; fits LDS (64 KiB u32)
#define NSLAB 256            // histogram slabs per graph
#define BORUVKA_ROUNDS 12

typedef __attribute__((ext_vector_type(8))) short short8;
typedef __attribute__((ext_vector_type(4))) float floatx4;

// ---------- helpers ----------
__device__ __forceinline__ unsigned bin_of(float v, float scale) {
  if (v < 0.f) v = 0.f;
  unsigned b = (unsigned)(v * scale);
  return b >= (unsigned)NBINS ? (unsigned)(NBINS - 1) : b;
}

// ---------- row squared norms for both graphs (fp32, matches reference) ----------
__global__ void k_rownorm(const float* __restrict__ x1, const float* __restrict__ x2,
                          float* __restrict__ sq) {
  int i = blockIdx.x * blockDim.x + threadIdx.x;
  if (i >= 2 * NN) return;
  const float* x = (i < NN) ? x1 : x2;
  int r = i & (NN - 1);
  const float* row = x + (size_t)r * DF;
  float s = 0.f;
  for (int k = 0; k < DF; ++k) s += row[k] * row[k];
  sq[i] = s;
}

// ---------- split fp32 -> (hi, lo) bf16 for error-compensated MFMA ----------
__global__ void k_split(const float* __restrict__ x1, const float* __restrict__ x2,
                        unsigned short* __restrict__ xh, unsigned short* __restrict__ xl) {
  int i = blockIdx.x * blockDim.x + threadIdx.x;
  if (i >= 2 * NN * DF) return;
  const float* x = (i < NN * DF) ? x1 : x2;
  float v = x[i & (NN * DF - 1)];
  unsigned u = __float_as_uint(v);
  unsigned hu = u & 0xffff0000u;
  float hf = __uint_as_float(hu);
  float lf = v - hf;
  unsigned lu = __float_as_uint(lf) & 0xffff0000u;
  xh[i] = (unsigned short)(hu >> 16);
  xl[i] = (unsigned short)(lu >> 16);
}

// ---------- distance matrix via split-bf16 MFMA Gram ----------
__global__ __launch_bounds__(256) void k_dist(const unsigned short* __restrict__ Xhi,
                                              const unsigned short* __restrict__ Xlo,
                                              const float* __restrict__ sq,
                                              float* __restrict__ Dbase,
                                              unsigned* __restrict__ caps) {
  int g = blockIdx.z;
  const unsigned short* xh = Xhi + (size_t)g * NN * DF;
  const unsigned short* xl = Xlo + (size_t)g * NN * DF;
  const float* sqg = sq + g * NN;
  float* D = Dbase + (size_t)g * NN * NN;
  __shared__ __align__(16) unsigned short Ah[64 * 32];
  __shared__ __align__(16) unsigned short Al[64 * 32];
  __shared__ __align__(16) unsigned short Bh[64 * 32];
  __shared__ __align__(16) unsigned short Bl[64 * 32];
  int i0 = blockIdx.y * 64, j0 = blockIdx.x * 64;
  int t = threadIdx.x;
  int w = t >> 6, lane = t & 63;
  int m = lane & 15, quad = lane >> 4;
  floatx4 acc[4];
  for (int s = 0; s < 4; ++s) acc[s] = (floatx4){0.f, 0.f, 0.f, 0.f};
  int srow = t >> 2, skp = (t & 3) * 8;
  for (int kc = 0; kc < DF; kc += 32) {
    if (kc) __syncthreads();
    *(short8*)&Ah[srow * 32 + skp] = *(const short8*)&xh[(size_t)(i0 + srow) * DF + kc + skp];
    *(short8*)&Al[srow * 32 + skp] = *(const short8*)&xl[(size_t)(i0 + srow) * DF + kc + skp];
    *(short8*)&Bh[srow * 32 + skp] = *(const short8*)&xh[(size_t)(j0 + srow) * DF + kc + skp];
    *(short8*)&Bl[srow * 32 + skp] = *(const short8*)&xl[(size_t)(j0 + srow) * DF + kc + skp];
    __syncthreads();
    short8 ah = *(const short8*)&Ah[(w * 16 + m) * 32 + quad * 8];
    short8 al = *(const short8*)&Al[(w * 16 + m) * 32 + quad * 8];
    for (int s = 0; s < 4; ++s) {
      short8 bh = *(const short8*)&Bh[(s * 16 + m) * 32 + quad * 8];
      short8 bl = *(const short8*)&Bl[(s * 16 + m) * 32 + quad * 8];
      acc[s] = __builtin_amdgcn_mfma_f32_16x16x32_bf16(ah, bh, acc[s], 0, 0, 0);
      acc[s] = __builtin_amdgcn_mfma_f32_16x16x32_bf16(ah, bl, acc[s], 0, 0, 0);
      acc[s] = __builtin_amdgcn_mfma_f32_16x16x32_bf16(al, bh, acc[s], 0, 0, 0);
    }
  }
  float mx = 0.f;
  int ib = i0 + w * 16 + quad * 4;
  for (int s = 0; s < 4; ++s) {
    int j = j0 + s * 16 + m;
    float sqj = sqg[j];
    for (int r = 0; r < 4; ++r) {
      int i = ib + r;
      float d2 = sqg[i] + sqj - 2.f * acc[s][r];
      d2 = fmaxf(d2, 0.f);
      float d = (d2 > 1e-12f) ? sqrtf(d2) : 0.f;
      mx = fmaxf(mx, d);
      D[(size_t)i * NN + j] = d;
    }
  }
  for (int off = 32; off > 0; off >>= 1) mx = fmaxf(mx, __shfl_down(mx, off, 64));
  __shared__ float wmax[4];
  if (lane == 0) wmax[w] = mx;
  __syncthreads();
  if (t == 0) {
    float mm = fmaxf(fmaxf(wmax[0], wmax[1]), fmaxf(wmax[2], wmax[3]));
    atomicMax(&caps[g], __float_as_uint(mm));
  }
}

// ---------- Boruvka init ----------
__global__ void k_binit(int* __restrict__ comp, unsigned long long* __restrict__ compbest,
                        int* __restrict__ mstcnt, int* __restrict__ ncomp) {
  int i = blockIdx.x * blockDim.x + threadIdx.x;
  if (i >= 2 * NN) return;
  comp[i] = i & (NN - 1);
  compbest[i] = ~0ull;
  if ((i & (NN - 1)) == 0) {
    mstcnt[i >> 12] = 0;
    ncomp[i >> 12] = NN;
  }
}

// ---------- Boruvka step 1: per-row min edge leaving own component ----------
__global__ __launch_bounds__(256) void k_minedge(const float* __restrict__ Dbase,
                                                 const int* __restrict__ comp_base,
                                                 unsigned long long* __restrict__ compbest_base,
                                                 const int* __restrict__ ncomp) {
  int g = blockIdx.y;
  if (ncomp[g] == 1) return;
  int v = blockIdx.x;
  const float* row = Dbase + ((size_t)g * NN + (size_t)v) * NN;
  const int* comp = comp_base + g * NN;
  unsigned long long* cbest = compbest_base + (size_t)g * NN;
  int cv = comp[v];
  int t = threadIdx.x;
  unsigned long long best = ~0ull;
  for (int j = t; j < NN; j += 256) {
    if (comp[j] != cv) {
      unsigned long long key = ((unsigned long long)__float_as_uint(row[j]) << 24) |
                               ((unsigned)v << 12) | (unsigned)j;
      if (key < best) best = key;
    }
  }
  for (int off = 32; off > 0; off >>= 1) {
    unsigned long long o = __shfl_down(best, off, 64);
    if (o < best) best = o;
  }
  __shared__ unsigned long long wmin[4];
  if ((t & 63) == 0) wmin[t >> 6] = best;
  __syncthreads();
  if (t == 0) {
    unsigned long long bb = wmin[0];
    for (int w = 1; w < 4; ++w)
      if (wmin[w] < bb) bb = wmin[w];
    if (bb != ~0ull) atomicMin(&cbest[cv], bb);
  }
}

// ---------- Boruvka step 2: hook/contract ----------
__global__ __launch_bounds__(1024) void k_hook(unsigned long long* __restrict__ compbest_base,
                                               int* __restrict__ comp_base,
                                               float* __restrict__ mstw_base,
                                               int* __restrict__ mstcnt,
                                               int* __restrict__ ncomp) {
  int g = blockIdx.x;
  if (ncomp[g] == 1) return;
  unsigned long long* cb = compbest_base + (size_t)g * NN;
  int* comp = comp_base + g * NN;
  float* mstw = mstw_base + g * (NN - 1);
  __shared__ int par[NN];
  __shared__ unsigned char live[NN];
  __shared__ int newcnt;
  int t = threadIdx.x;
  if (t == 0) newcnt = 0;
  for (int c = t; c < NN; c += 1024) {
    unsigned long long key = cb[c];
    bool a = (key != ~0ull);
    live[c] = a ? 1 : 0;
    int p = c;
    if (a) {
      int j = (int)(key & 0xfffull);
      p = comp[j];
    }
    par[c] = p;
  }
  __syncthreads();
  for (int c = t; c < NN; c += 1024) {
    int p = par[c];
    if (p != c && par[p] == c && c < p) par[c] = c;
  }
  __syncthreads();
  for (int c = t; c < NN; c += 1024) {
    if (live[c] && par[c] != c) {
      unsigned long long key = cb[c];
      float w = __uint_as_float((unsigned)(key >> 24));
      int slot = atomicAdd(&mstcnt[g], 1);
      mstw[slot] = w;
    }
  }
  __syncthreads();
  for (int it = 0; it < 12; ++it) {
    int np[NN / 1024];
    for (int c = t, k = 0; c < NN; c += 1024, ++k) np[k] = par[par[c]];
    __syncthreads();
    for (int c = t, k = 0; c < NN; c += 1024, ++k) par[c] = np[k];
    __syncthreads();
  }
  int cnt = 0;
  for (int c = t; c < NN; c += 1024)
    if (live[c] && par[c] == c) cnt++;
  for (int off = 32; off > 0; off >>= 1) cnt += __shfl_down(cnt, off, 64);
  if ((t & 63) == 0 && cnt) atomicAdd(&newcnt, cnt);
  for (int v = t; v < NN; v += 1024) comp[v] = par[comp[v]];
  for (int c = t; c < NN; c += 1024) cb[c] = ~0ull;
  __syncthreads();
  if (t == 0) ncomp[g] = newcnt;
}

// ---------- histogram: per-block LDS hist over upper triangle, slab dump ----------
// block b: g = b>>8, s = b&255 -> rows {p, NN-1-p} for p = s, s+256, ... (8 row-pairs)
__global__ __launch_bounds__(256) void k_hist(const float* __restrict__ Dbase,
                                              const unsigned* __restrict__ caps,
                                              unsigned* __restrict__ Hs) {
  __shared__ unsigned h[NBINS];
  int t = threadIdx.x;
  for (int i = t; i < NBINS; i += 256) h[i] = 0;
  int b = blockIdx.x;
  int g = b >> 8, s = b & (NSLAB - 1);
  const float* D = Dbase + (size_t)g * NN * NN;
  float cap = __uint_as_float(caps[g]);
  float capmax = fmaxf(__uint_as_float(caps[0]), __uint_as_float(caps[1]));
  float scale = (float)NBINS / capmax;
  __syncthreads();
  for (int p = s; p < NN / 2; p += NSLAB) {
    int r1 = p, r2 = NN - 1 - p;
    const float* row1 = D + (size_t)r1 * NN;
    const float* row2 = D + (size_t)r2 * NN;
    for (int j = r1 + 1 + t; j < NN; j += 256)
      atomicAdd(&h[bin_of(cap - row1[j], scale)], 1u);
    for (int j = r2 + 1 + t; j < NN; j += 256)
      atomicAdd(&h[bin_of(cap - row2[j], scale)], 1u);
  }
  __syncthreads();
  unsigned* slab = Hs + (size_t)b * NBINS;
  for (int i = t; i < NBINS; i += 256) slab[i] = h[i];
}

// ---------- move tree edges to persistence 0 (on slab 0 of each graph; wrap-safe) ----------
__global__ void k_treefix(const float* __restrict__ twbase, const unsigned* __restrict__ caps,
                          unsigned* __restrict__ Hs) {
  int g = blockIdx.y;
  unsigned* hist = Hs + (size_t)(g * NSLAB) * NBINS;
  float cap = __uint_as_float(caps[g]);
  float capmax = fmaxf(__uint_as_float(caps[0]), __uint_as_float(caps[1]));
  float scale = (float)NBINS / capmax;
  int idx = blockIdx.x * blockDim.x + threadIdx.x;
  if (idx < NN - 1) {
    float w = twbase[g * (NN - 1) + idx];
    atomicSub(&hist[bin_of(cap - w, scale)], 1u);  // may wrap; per-bin total stays >= 0
    atomicAdd(&hist[0], 1u);
  }
}

// ---------- merge 256 slabs per graph -> Hm[2][NBINS] ----------
__global__ __launch_bounds__(256) void k_merge(const unsigned* __restrict__ Hs,
                                               unsigned* __restrict__ Hm) {
  int id = blockIdx.x * 256 + threadIdx.x;  // 0 .. 2*NBINS-1
  int g = id >> 14;
  int i = id & (NBINS - 1);
  const unsigned* base = Hs + (size_t)(g * NSLAB) * NBINS + i;
  unsigned sum = 0;
  for (int s = 0; s < NSLAB; ++s) sum += base[(size_t)s * NBINS];
  Hm[id] = sum;
}

// ---------- W1: single block computes sum |running prefix| * dt ----------
__global__ __launch_bounds__(256) void k_w1(const unsigned* __restrict__ Hm,
                                            const unsigned* __restrict__ caps,
                                            float* __restrict__ out) {
  int t = threadIdx.x;
  const int PB = NBINS / 256;  // 64 bins per thread
  int base = t * PB;
  long long tsum = 0;
  for (int i = 0; i < PB; ++i)
    tsum += (long long)(int)(Hm[base + i] - Hm[NBINS + base + i]);
  int lane = t & 63, wid = t >> 6;
  long long incl = tsum;
  for (int off = 1; off < 64; off <<= 1) {
    long long o = __shfl_up(incl, off, 64);
    if (lane >= off) incl += o;
  }
  __shared__ long long wtot[4];
  if (lane == 63) wtot[wid] = incl;
  __syncthreads();
  long long run = incl - tsum;
  for (int w = 0; w < wid; ++w) run += wtot[w];
  unsigned long long local = 0;
  for (int i = 0; i < PB; ++i) {
    run += (long long)(int)(Hm[base + i] - Hm[NBINS + base + i]);
    local += (unsigned long long)(run < 0 ? -run : run);
  }
  for (int off = 32; off > 0; off >>= 1) local += __shfl_down(local, off, 64);
  __shared__ unsigned long long wl[4];
  if (lane == 0) wl[wid] = local;
  __syncthreads();
  if (t == 0) {
    float capmax = fmaxf(__uint_as_float(caps[0]), __uint_as_float(caps[1]));
    double dt = (double)capmax / (double)NBINS;
    out[0] = (float)((double)(wl[0] + wl[1] + wl[2] + wl[3]) * dt);
  }
}

__global__ void k_fail(float* out) { out[0] = -1234567.0f; }

extern "C" void kernel_launch(void* const* d_in, const int* in_sizes, int n_in,
                              void* d_out, int out_size, void* d_ws, size_t ws_size,
                              hipStream_t stream) {
  const float* x1 = (const float*)d_in[0];
  const float* x2 = (const float*)d_in[2];
  float* out = (float*)d_out;
  char* ws = (char*)d_ws;

  const size_t offD = 0;                                        // 128 MiB D matrices
  const size_t offS = 2ull * NN * NN * 4ull;                    // 512 slabs x 64 KiB = 32 MiB
  const size_t offHm = offS + 2ull * NSLAB * NBINS * 4ull;      // 128 KiB merged hist
  const size_t offHdr = offHm + 2ull * NBINS * 4ull;            // caps(8) + pad
  const size_t offSq = offHdr + 64;
  const size_t offTw = offSq + 2ull * NN * 4ull;
  const size_t offCb = (offTw + 2ull * (NN - 1) * 4ull + 7ull) & ~7ull;
  const size_t offCp = offCb + 2ull * NN * 8ull;
  const size_t offMeta = offCp + 2ull * NN * 4ull;
  const size_t needed = offMeta + 64;
  if (ws_size < needed) {
    hipLaunchKernelGGL(k_fail, dim3(1), dim3(1), 0, stream, out);
    return;
  }

  float* Dbase = (float*)(ws + offD);
  unsigned* Hs = (unsigned*)(ws + offS);
  // Xhi/Xlo (4 MiB total) transiently live in the slab region (fully overwritten by k_hist)
  unsigned short* Xhi = (unsigned short*)(ws + offS);
  unsigned short* Xlo = (unsigned short*)(ws + offS + 2ull * NN * DF * 2ull);
  unsigned* Hm = (unsigned*)(ws + offHm);
  unsigned* caps = (unsigned*)(ws + offHdr);
  float* sq = (float*)(ws + offSq);
  float* tw = (float*)(ws + offTw);
  unsigned long long* compbest = (unsigned long long*)(ws + offCb);
  int* comp = (int*)(ws + offCp);
  int* mstcnt = (int*)(ws + offMeta);
  int* ncomp = (int*)(ws + offMeta + 8);

  // zero caps only (64 B) — slabs are fully overwritten, Hm fully written by k_merge
  hipMemsetAsync(ws + offHdr, 0, 64, stream);

  hipLaunchKernelGGL(k_rownorm, dim3((2 * NN + 255) / 256), dim3(256), 0, stream, x1, x2, sq);
  hipLaunchKernelGGL(k_split, dim3((2 * NN * DF + 255) / 256), dim3(256), 0, stream,
                     x1, x2, Xhi, Xlo);
  hipLaunchKernelGGL(k_dist, dim3(64, 64, 2), dim3(256), 0, stream, Xhi, Xlo, sq, Dbase, caps);
  hipLaunchKernelGGL(k_binit, dim3((2 * NN + 255) / 256), dim3(256), 0, stream,
                     comp, compbest, mstcnt, ncomp);
  for (int r = 0; r < BORUVKA_ROUNDS; ++r) {
    hipLaunchKernelGGL(k_minedge, dim3(NN, 2), dim3(256), 0, stream,
                       Dbase, comp, compbest, ncomp);
    hipLaunchKernelGGL(k_hook, dim3(2), dim3(1024), 0, stream,
                       compbest, comp, tw, mstcnt, ncomp);
  }
  hipLaunchKernelGGL(k_hist, dim3(2 * NSLAB), dim3(256), 0, stream, Dbase, caps, Hs);
  hipLaunchKernelGGL(k_treefix, dim3(16, 2), dim3(256), 0, stream, tw, caps, Hs);
  hipLaunchKernelGGL(k_merge, dim3(2 * NBINS / 256), dim3(256), 0, stream, Hs, Hm);
  hipLaunchKernelGGL(k_w1, dim3(1), dim3(256), 0, stream, Hm, caps, out);
}

// Round 6
// 482.174 us; speedup vs baseline: 2.5707x; 1.1781x over previous
//
#include <hip/hip_runtime.h>
#include <stdint.h>

#define NN 4096
#define DF 128
#define NBINS 16384          // fine bins; fits LDS (64 KiB u32)
#define NSLAB 256            // histogram slabs per graph
#define BORUVKA_ROUNDS 12
#define PAD 40               // LDS row stride (u16) — breaks b128 bank aliasing

typedef __attribute__((ext_vector_type(8))) short short8;
typedef __attribute__((ext_vector_type(4))) float floatx4;
typedef __attribute__((ext_vector_type(4))) unsigned short ushort4_t;
typedef __attribute__((ext_vector_type(4))) int int4_t;

// ---------- helpers ----------
__device__ __forceinline__ unsigned bin_of(float v, float scale) {
  if (v < 0.f) v = 0.f;
  unsigned b = (unsigned)(v * scale);
  return b >= (unsigned)NBINS ? (unsigned)(NBINS - 1) : b;
}

// ---------- row squared norms for both graphs (fp32, matches reference) ----------
__global__ void k_rownorm(const float* __restrict__ x1, const float* __restrict__ x2,
                          float* __restrict__ sq) {
  int i = blockIdx.x * blockDim.x + threadIdx.x;
  if (i >= 2 * NN) return;
  const float* x = (i < NN) ? x1 : x2;
  int r = i & (NN - 1);
  const float* row = x + (size_t)r * DF;
  float s = 0.f;
  for (int k = 0; k < DF; ++k) s += row[k] * row[k];
  sq[i] = s;
}

// ---------- distance upper bound -> u16 quantization scales ----------
// hdrf: [0..1]=caps(u32), [2]=qscale, [3]=qinv
__global__ __launch_bounds__(256) void k_bound(const float* __restrict__ sq,
                                               float* __restrict__ hdrf) {
  int t = threadIdx.x;
  float m = 0.f;
  for (int i = t; i < 2 * NN; i += 256) m = fmaxf(m, sq[i]);
  for (int off = 32; off > 0; off >>= 1) m = fmaxf(m, __shfl_down(m, off, 64));
  __shared__ float wm[4];
  if ((t & 63) == 0) wm[t >> 6] = m;
  __syncthreads();
  if (t == 0) {
    float mm = fmaxf(fmaxf(wm[0], wm[1]), fmaxf(wm[2], wm[3]));
    float dbound = 2.f * sqrtf(mm);       // d <= |xi|+|xj| <= 2*max|x|
    hdrf[2] = 65535.f / dbound;
    hdrf[3] = dbound / 65535.f;
  }
}

// ---------- split fp32 -> (hi, lo) bf16 for error-compensated MFMA ----------
__global__ void k_split(const float* __restrict__ x1, const float* __restrict__ x2,
                        unsigned short* __restrict__ xh, unsigned short* __restrict__ xl) {
  int i = blockIdx.x * blockDim.x + threadIdx.x;
  if (i >= 2 * NN * DF) return;
  const float* x = (i < NN * DF) ? x1 : x2;
  float v = x[i & (NN * DF - 1)];
  unsigned u = __float_as_uint(v);
  unsigned hu = u & 0xffff0000u;
  float hf = __uint_as_float(hu);
  float lf = v - hf;
  unsigned lu = __float_as_uint(lf) & 0xffff0000u;
  xh[i] = (unsigned short)(hu >> 16);
  xl[i] = (unsigned short)(lu >> 16);
}

// ---------- distances via split-bf16 MFMA Gram; emit u16-quantized D + fp32 cap ----------
__global__ __launch_bounds__(256) void k_dist(const unsigned short* __restrict__ Xhi,
                                              const unsigned short* __restrict__ Xlo,
                                              const float* __restrict__ sq,
                                              const float* __restrict__ hdrf,
                                              unsigned short* __restrict__ Qbase,
                                              unsigned* __restrict__ caps) {
  int g = blockIdx.z;
  const unsigned short* xh = Xhi + (size_t)g * NN * DF;
  const unsigned short* xl = Xlo + (size_t)g * NN * DF;
  const float* sqg = sq + g * NN;
  unsigned short* Q = Qbase + (size_t)g * NN * NN;
  float qs = hdrf[2];
  __shared__ __align__(16) unsigned short Ah[64 * PAD];
  __shared__ __align__(16) unsigned short Al[64 * PAD];
  __shared__ __align__(16) unsigned short Bh[64 * PAD];
  __shared__ __align__(16) unsigned short Bl[64 * PAD];
  int i0 = blockIdx.y * 64, j0 = blockIdx.x * 64;
  int t = threadIdx.x;
  int w = t >> 6, lane = t & 63;
  int m = lane & 15, quad = lane >> 4;
  floatx4 acc[4];
  for (int s = 0; s < 4; ++s) acc[s] = (floatx4){0.f, 0.f, 0.f, 0.f};
  int srow = t >> 2, skp = (t & 3) * 8;
  for (int kc = 0; kc < DF; kc += 32) {
    if (kc) __syncthreads();
    *(short8*)&Ah[srow * PAD + skp] = *(const short8*)&xh[(size_t)(i0 + srow) * DF + kc + skp];
    *(short8*)&Al[srow * PAD + skp] = *(const short8*)&xl[(size_t)(i0 + srow) * DF + kc + skp];
    *(short8*)&Bh[srow * PAD + skp] = *(const short8*)&xh[(size_t)(j0 + srow) * DF + kc + skp];
    *(short8*)&Bl[srow * PAD + skp] = *(const short8*)&xl[(size_t)(j0 + srow) * DF + kc + skp];
    __syncthreads();
    short8 ah = *(const short8*)&Ah[(w * 16 + m) * PAD + quad * 8];
    short8 al = *(const short8*)&Al[(w * 16 + m) * PAD + quad * 8];
    for (int s = 0; s < 4; ++s) {
      short8 bh = *(const short8*)&Bh[(s * 16 + m) * PAD + quad * 8];
      short8 bl = *(const short8*)&Bl[(s * 16 + m) * PAD + quad * 8];
      acc[s] = __builtin_amdgcn_mfma_f32_16x16x32_bf16(ah, bh, acc[s], 0, 0, 0);
      acc[s] = __builtin_amdgcn_mfma_f32_16x16x32_bf16(ah, bl, acc[s], 0, 0, 0);
      acc[s] = __builtin_amdgcn_mfma_f32_16x16x32_bf16(al, bh, acc[s], 0, 0, 0);
    }
  }
  // C/D layout: col = lane&15 (j), row = quad*4 + reg (i)
  float mx = 0.f;
  int ib = i0 + w * 16 + quad * 4;
  for (int s = 0; s < 4; ++s) {
    int j = j0 + s * 16 + m;
    float sqj = sqg[j];
    for (int r = 0; r < 4; ++r) {
      int i = ib + r;
      float d2 = sqg[i] + sqj - 2.f * acc[s][r];
      d2 = fmaxf(d2, 0.f);
      float d = (d2 > 1e-12f) ? sqrtf(d2) : 0.f;
      mx = fmaxf(mx, d);
      unsigned q = (unsigned)(d * qs + 0.5f);
      if (q > 65535u) q = 65535u;
      Q[(size_t)i * NN + j] = (unsigned short)q;
    }
  }
  for (int off = 32; off > 0; off >>= 1) mx = fmaxf(mx, __shfl_down(mx, off, 64));
  __shared__ float wmax[4];
  if (lane == 0) wmax[w] = mx;
  __syncthreads();
  if (t == 0) {
    float mm = fmaxf(fmaxf(wmax[0], wmax[1]), fmaxf(wmax[2], wmax[3]));
    atomicMax(&caps[g], __float_as_uint(mm));
  }
}

// ---------- Boruvka init ----------
__global__ void k_binit(int* __restrict__ comp, unsigned long long* __restrict__ compbest,
                        unsigned long long* __restrict__ bestkey,
                        int* __restrict__ mstcnt, int* __restrict__ ncomp) {
  int i = blockIdx.x * blockDim.x + threadIdx.x;
  if (i >= 2 * NN) return;
  comp[i] = i & (NN - 1);
  compbest[i] = ~0ull;
  bestkey[i] = ~0ull;
  if ((i & (NN - 1)) == 0) {
    mstcnt[i >> 12] = 0;
    ncomp[i >> 12] = NN;
  }
}

// ---------- Boruvka step 1: per-row min edge leaving own component ----------
// key = (w16 << 24) | (v << 12) | j  (unique => hook graph has only 2-cycles).
// Cached candidate: valid while its target stays outside comp[v] (outside-set
// only shrinks, and the superset argmin inside the subset is the subset min).
__global__ __launch_bounds__(256) void k_minedge(const unsigned short* __restrict__ Qbase,
                                                 const int* __restrict__ comp_base,
                                                 unsigned long long* __restrict__ compbest_base,
                                                 unsigned long long* __restrict__ bestkey_base,
                                                 const int* __restrict__ ncomp) {
  int g = blockIdx.y;
  if (ncomp[g] == 1) return;
  int v = blockIdx.x;
  const int* comp = comp_base + g * NN;
  unsigned long long* cbest = compbest_base + (size_t)g * NN;
  unsigned long long* bkp = bestkey_base + (size_t)g * NN;
  int cv = comp[v];
  int t = threadIdx.x;
  unsigned long long bk = bkp[v];
  if (bk != ~0ull) {
    int bj = (int)(bk & 0xfffull);
    if (comp[bj] != cv) {           // cache still valid: skip the row scan
      if (t == 0) atomicMin(&cbest[cv], bk);
      return;
    }
  }
  const unsigned short* row = Qbase + ((size_t)g * NN + (size_t)v) * NN;
  unsigned long long best = ~0ull;
  for (int jb = t * 4; jb < NN; jb += 1024) {
    ushort4_t rw = *(const ushort4_t*)&row[jb];
    int4_t cj = *(const int4_t*)&comp[jb];
    for (int u = 0; u < 4; ++u) {
      if (cj[u] != cv) {
        unsigned long long key = ((unsigned long long)rw[u] << 24) |
                                 ((unsigned long long)v << 12) | (unsigned)(jb + u);
        if (key < best) best = key;
      }
    }
  }
  for (int off = 32; off > 0; off >>= 1) {
    unsigned long long o = __shfl_down(best, off, 64);
    if (o < best) best = o;
  }
  __shared__ unsigned long long wmin[4];
  if ((t & 63) == 0) wmin[t >> 6] = best;
  __syncthreads();
  if (t == 0) {
    unsigned long long bb = wmin[0];
    for (int w = 1; w < 4; ++w)
      if (wmin[w] < bb) bb = wmin[w];
    bkp[v] = bb;
    if (bb != ~0ull) atomicMin(&cbest[cv], bb);
  }
}

// ---------- Boruvka step 2: hook/contract ----------
__global__ __launch_bounds__(1024) void k_hook(unsigned long long* __restrict__ compbest_base,
                                               int* __restrict__ comp_base,
                                               const float* __restrict__ hdrf,
                                               float* __restrict__ mstw_base,
                                               int* __restrict__ mstcnt,
                                               int* __restrict__ ncomp) {
  int g = blockIdx.x;
  if (ncomp[g] == 1) return;
  unsigned long long* cb = compbest_base + (size_t)g * NN;
  int* comp = comp_base + g * NN;
  float* mstw = mstw_base + g * (NN - 1);
  float qinv = hdrf[3];
  __shared__ int par[NN];
  __shared__ unsigned char live[NN];
  __shared__ int newcnt;
  int t = threadIdx.x;
  if (t == 0) newcnt = 0;
  for (int c = t; c < NN; c += 1024) {
    unsigned long long key = cb[c];
    bool a = (key != ~0ull);
    live[c] = a ? 1 : 0;
    int p = c;
    if (a) {
      int j = (int)(key & 0xfffull);
      p = comp[j];
    }
    par[c] = p;
  }
  __syncthreads();
  for (int c = t; c < NN; c += 1024) {
    int p = par[c];
    if (p != c && par[p] == c && c < p) par[c] = c;
  }
  __syncthreads();
  for (int c = t; c < NN; c += 1024) {
    if (live[c] && par[c] != c) {
      unsigned long long key = cb[c];
      float w = (float)((unsigned)(key >> 24)) * qinv;  // dequantized MST weight
      int slot = atomicAdd(&mstcnt[g], 1);
      mstw[slot] = w;
    }
  }
  __syncthreads();
  for (int it = 0; it < 12; ++it) {
    int np[NN / 1024];
    for (int c = t, k = 0; c < NN; c += 1024, ++k) np[k] = par[par[c]];
    __syncthreads();
    for (int c = t, k = 0; c < NN; c += 1024, ++k) par[c] = np[k];
    __syncthreads();
  }
  int cnt = 0;
  for (int c = t; c < NN; c += 1024)
    if (live[c] && par[c] == c) cnt++;
  for (int off = 32; off > 0; off >>= 1) cnt += __shfl_down(cnt, off, 64);
  if ((t & 63) == 0 && cnt) atomicAdd(&newcnt, cnt);
  for (int v = t; v < NN; v += 1024) comp[v] = par[comp[v]];
  for (int c = t; c < NN; c += 1024) cb[c] = ~0ull;
  __syncthreads();
  if (t == 0) ncomp[g] = newcnt;
}

// ---------- histogram: per-block LDS hist over upper triangle (u16 D), slab dump ----------
__global__ __launch_bounds__(256) void k_hist(const unsigned short* __restrict__ Qbase,
                                              const unsigned* __restrict__ caps,
                                              const float* __restrict__ hdrf,
                                              unsigned* __restrict__ Hs) {
  __shared__ unsigned h[NBINS];
  int t = threadIdx.x;
  for (int i = t; i < NBINS; i += 256) h[i] = 0;
  int b = blockIdx.x;
  int g = b >> 8, s = b & (NSLAB - 1);
  const unsigned short* Q = Qbase + (size_t)g * NN * NN;
  float cap = __uint_as_float(caps[g]);
  float capmax = fmaxf(__uint_as_float(caps[0]), __uint_as_float(caps[1]));
  float scale = (float)NBINS / capmax;
  float qinv = hdrf[3];
  __syncthreads();
  for (int p = s; p < NN / 2; p += NSLAB) {
    int r1 = p, r2 = NN - 1 - p;
    const unsigned short* row1 = Q + (size_t)r1 * NN;
    const unsigned short* row2 = Q + (size_t)r2 * NN;
    for (int j = r1 + 1 + t; j < NN; j += 256)
      atomicAdd(&h[bin_of(cap - (float)row1[j] * qinv, scale)], 1u);
    for (int j = r2 + 1 + t; j < NN; j += 256)
      atomicAdd(&h[bin_of(cap - (float)row2[j] * qinv, scale)], 1u);
  }
  __syncthreads();
  unsigned* slab = Hs + (size_t)b * NBINS;
  for (int i = t; i < NBINS; i += 256) slab[i] = h[i];
}

// ---------- move tree edges to persistence 0 (slab 0; same dequant grid => exact) ----------
__global__ void k_treefix(const float* __restrict__ twbase, const unsigned* __restrict__ caps,
                          unsigned* __restrict__ Hs) {
  int g = blockIdx.y;
  unsigned* hist = Hs + (size_t)(g * NSLAB) * NBINS;
  float cap = __uint_as_float(caps[g]);
  float capmax = fmaxf(__uint_as_float(caps[0]), __uint_as_float(caps[1]));
  float scale = (float)NBINS / capmax;
  int idx = blockIdx.x * blockDim.x + threadIdx.x;
  if (idx < NN - 1) {
    float w = twbase[g * (NN - 1) + idx];
    atomicSub(&hist[bin_of(cap - w, scale)], 1u);  // may wrap; per-bin total stays >= 0
    atomicAdd(&hist[0], 1u);
  }
}

// ---------- merge 256 slabs per graph -> Hm[2][NBINS] ----------
__global__ __launch_bounds__(256) void k_merge(const unsigned* __restrict__ Hs,
                                               unsigned* __restrict__ Hm) {
  int id = blockIdx.x * 256 + threadIdx.x;  // 0 .. 2*NBINS-1
  int g = id >> 14;
  int i = id & (NBINS - 1);
  const unsigned* base = Hs + (size_t)(g * NSLAB) * NBINS + i;
  unsigned sum = 0;
  for (int s = 0; s < NSLAB; ++s) sum += base[(size_t)s * NBINS];
  Hm[id] = sum;
}

// ---------- W1: single block computes sum |running prefix| * dt ----------
__global__ __launch_bounds__(256) void k_w1(const unsigned* __restrict__ Hm,
                                            const unsigned* __restrict__ caps,
                                            float* __restrict__ out) {
  int t = threadIdx.x;
  const int PB = NBINS / 256;  // 64 bins per thread
  int base = t * PB;
  long long tsum = 0;
  for (int i = 0; i < PB; ++i)
    tsum += (long long)(int)(Hm[base + i] - Hm[NBINS + base + i]);
  int lane = t & 63, wid = t >> 6;
  long long incl = tsum;
  for (int off = 1; off < 64; off <<= 1) {
    long long o = __shfl_up(incl, off, 64);
    if (lane >= off) incl += o;
  }
  __shared__ long long wtot[4];
  if (lane == 63) wtot[wid] = incl;
  __syncthreads();
  long long run = incl - tsum;
  for (int w = 0; w < wid; ++w) run += wtot[w];
  unsigned long long local = 0;
  for (int i = 0; i < PB; ++i) {
    run += (long long)(int)(Hm[base + i] - Hm[NBINS + base + i]);
    local += (unsigned long long)(run < 0 ? -run : run);
  }
  for (int off = 32; off > 0; off >>= 1) local += __shfl_down(local, off, 64);
  __shared__ unsigned long long wl[4];
  if (lane == 0) wl[wid] = local;
  __syncthreads();
  if (t == 0) {
    float capmax = fmaxf(__uint_as_float(caps[0]), __uint_as_float(caps[1]));
    double dt = (double)capmax / (double)NBINS;
    out[0] = (float)((double)(wl[0] + wl[1] + wl[2] + wl[3]) * dt);
  }
}

__global__ void k_fail(float* out) { out[0] = -1234567.0f; }

extern "C" void kernel_launch(void* const* d_in, const int* in_sizes, int n_in,
                              void* d_out, int out_size, void* d_ws, size_t ws_size,
                              hipStream_t stream) {
  const float* x1 = (const float*)d_in[0];
  const float* x2 = (const float*)d_in[2];
  float* out = (float*)d_out;
  char* ws = (char*)d_ws;

  const size_t offQ = 0;                                        // u16 D: 64 MiB
  const size_t offS = 2ull * NN * NN * 2ull;                    // slabs: 32 MiB
  const size_t offHm = offS + 2ull * NSLAB * NBINS * 4ull;      // 128 KiB merged hist
  const size_t offHdr = offHm + 2ull * NBINS * 4ull;            // caps+qscale+qinv
  const size_t offSq = offHdr + 64;
  const size_t offTw = offSq + 2ull * NN * 4ull;
  const size_t offCb = (offTw + 2ull * (NN - 1) * 4ull + 7ull) & ~7ull;
  const size_t offBk = offCb + 2ull * NN * 8ull;                // bestkey cache
  const size_t offCp = offBk + 2ull * NN * 8ull;
  const size_t offMeta = offCp + 2ull * NN * 4ull;
  const size_t needed = offMeta + 64;
  if (ws_size < needed) {
    hipLaunchKernelGGL(k_fail, dim3(1), dim3(1), 0, stream, out);
    return;
  }

  unsigned short* Qbase = (unsigned short*)(ws + offQ);
  unsigned* Hs = (unsigned*)(ws + offS);
  // Xhi/Xlo (4 MiB) transiently live in the slab region (dead before k_hist writes it)
  unsigned short* Xhi = (unsigned short*)(ws + offS);
  unsigned short* Xlo = (unsigned short*)(ws + offS + 2ull * NN * DF * 2ull);
  unsigned* Hm = (unsigned*)(ws + offHm);
  unsigned* caps = (unsigned*)(ws + offHdr);
  float* hdrf = (float*)(ws + offHdr);
  float* sq = (float*)(ws + offSq);
  float* tw = (float*)(ws + offTw);
  unsigned long long* compbest = (unsigned long long*)(ws + offCb);
  unsigned long long* bestkey = (unsigned long long*)(ws + offBk);
  int* comp = (int*)(ws + offCp);
  int* mstcnt = (int*)(ws + offMeta);
  int* ncomp = (int*)(ws + offMeta + 8);

  // zero header (caps; qscale/qinv overwritten by k_bound)
  hipMemsetAsync(ws + offHdr, 0, 64, stream);

  hipLaunchKernelGGL(k_rownorm, dim3((2 * NN + 255) / 256), dim3(256), 0, stream, x1, x2, sq);
  hipLaunchKernelGGL(k_bound, dim3(1), dim3(256), 0, stream, sq, hdrf);
  hipLaunchKernelGGL(k_split, dim3((2 * NN * DF + 255) / 256), dim3(256), 0, stream,
                     x1, x2, Xhi, Xlo);
  hipLaunchKernelGGL(k_dist, dim3(64, 64, 2), dim3(256), 0, stream,
                     Xhi, Xlo, sq, hdrf, Qbase, caps);
  hipLaunchKernelGGL(k_binit, dim3((2 * NN + 255) / 256), dim3(256), 0, stream,
                     comp, compbest, bestkey, mstcnt, ncomp);
  for (int r = 0; r < BORUVKA_ROUNDS; ++r) {
    hipLaunchKernelGGL(k_minedge, dim3(NN, 2), dim3(256), 0, stream,
                       Qbase, comp, compbest, bestkey, ncomp);
    hipLaunchKernelGGL(k_hook, dim3(2), dim3(1024), 0, stream,
                       compbest, comp, hdrf, tw, mstcnt, ncomp);
  }
  hipLaunchKernelGGL(k_hist, dim3(2 * NSLAB), dim3(256), 0, stream, Qbase, caps, hdrf, Hs);
  hipLaunchKernelGGL(k_treefix, dim3(16, 2), dim3(256), 0, stream, tw, caps, Hs);
  hipLaunchKernelGGL(k_merge, dim3(2 * NBINS / 256), dim3(256), 0, stream, Hs, Hm);
  hipLaunchKernelGGL(k_w1, dim3(1), dim3(256), 0, stream, Hm, caps, out);
}